// Round 3
// baseline (343.530 us; speedup 1.0000x reference)
//
#include <hip/hip_runtime.h>
#include <hip/hip_bf16.h>

typedef unsigned short u16;
typedef unsigned long long u64;
using bf16x8 = __attribute__((ext_vector_type(8))) short;
using f32x4v = __attribute__((ext_vector_type(4))) float;
typedef float v2f __attribute__((ext_vector_type(2)));

#define HC 256     // H*C
#define CDIM 64

__device__ __forceinline__ float b2f(u16 u){
  union { unsigned int i; float f; } c; c.i = ((unsigned)u) << 16; return c.f;
}
__device__ __forceinline__ u16 f2b(float f){
  union { float f; unsigned int i; } c; c.f = f;
  unsigned int x = c.i;
  return (u16)((x + 0x7FFFu + ((x >> 16) & 1u)) >> 16);   // RNE
}
// flag-aware external load: isbf=1 -> data is bf16, else fp32
__device__ __forceinline__ float ldf(const void* p, size_t i, int isbf){
  return isbf ? b2f(((const u16*)p)[i]) : ((const float*)p)[i];
}
__device__ __forceinline__ float sel4(float4 v, int h){ return h==0?v.x:(h==1?v.y:(h==2?v.z:v.w)); }
__device__ __forceinline__ float lrelu(float v){ return v>0.f ? v : 0.2f*v; }
// cross-lane fetch of a float by byte-addressed lane index (addr = lane*4)
__device__ __forceinline__ float wshf(float v, int addr4){
  return __int_as_float(__builtin_amdgcn_ds_bpermute(addr4, __float_as_int(v)));
}

// async global->LDS copy, 16B per lane; lds dest = wave-uniform base + lane*16
__device__ __forceinline__ void glds16(const void* g, void* l){
  __builtin_amdgcn_global_load_lds(
      (const __attribute__((address_space(1))) unsigned int*)g,
      (__attribute__((address_space(3))) unsigned int*)l, 16, 0, 0);
}

__device__ __forceinline__ float4 wave_max4(float4 m){
  #pragma unroll
  for(int o=32;o>0;o>>=1){
    m.x=fmaxf(m.x,__shfl_xor(m.x,o));
    m.y=fmaxf(m.y,__shfl_xor(m.y,o));
    m.z=fmaxf(m.z,__shfl_xor(m.z,o));
    m.w=fmaxf(m.w,__shfl_xor(m.w,o));
  }
  return m;
}
__device__ __forceinline__ float4 wave_sum4(float4 m){
  #pragma unroll
  for(int o=32;o>0;o>>=1){
    m.x+=__shfl_xor(m.x,o);
    m.y+=__shfl_xor(m.y,o);
    m.z+=__shfl_xor(m.z,o);
    m.w+=__shfl_xor(m.w,o);
  }
  return m;
}

// ---------------- hist (+rank capture) + dtype detect + prep (merged) ----------------
// blocks [0,eb): rank[e] = arrival index within dst bucket; block 0 also writes flag.
// blocks [eb,eb+385): weight prep (re-derives dtype flag locally -> no dependency).
__global__ void k_hist_prep(const int* __restrict__ dst, int E, int N, int* __restrict__ deg,
                            int* __restrict__ rank,
                            const u16* __restrict__ x, int nelem, int* __restrict__ flag,
                            const void* __restrict__ W1, const void* __restrict__ W2,
                            const void* __restrict__ We1, const void* __restrict__ ae1,
                            const void* __restrict__ We2, const void* __restrict__ ae2,
                            u16* __restrict__ Bt1, u16* __restrict__ Bt2, float* __restrict__ ce){
  int eb = (E + 255) >> 8;
  int t = threadIdx.x;
  if ((int)blockIdx.x < eb){
    int e = blockIdx.x*256 + t;
    if (e < E){
      int d = dst[e];
      if ((unsigned)d < (unsigned)N) rank[e] = atomicAdd(&deg[d], 1);
    }
    if (blockIdx.x == 0){
      __shared__ int bad0;
      if (t==0) bad0 = 0;
      __syncthreads();
      int n = nelem < 8192 ? nelem : 8192;
      int localbad = 0;
      for (int i=t; i<n; i+=256){
        int ex = (x[i] >> 7) & 0xFF;
        if (ex >= 140) localbad++;
      }
      if (localbad) atomicAdd(&bad0, 1);
      __syncthreads();
      if (t==0) *flag = (bad0==0) ? 1 : 0;   // 1 = bf16, 0 = fp32
    }
    return;
  }
  // ---- prep part: local dtype detect ----
  __shared__ int bad;
  if (t==0) bad = 0;
  __syncthreads();
  {
    int n = nelem < 8192 ? nelem : 8192;
    int localbad = 0;
    for (int i=t; i<n; i+=256){
      int ex = (x[i] >> 7) & 0xFF;
      if (ex >= 140) localbad++;
    }
    if (localbad) atomicAdd(&bad, 1);
  }
  __syncthreads();
  int bf = (bad==0) ? 1 : 0;
  int b = blockIdx.x - eb;
  if (b < 128){
    Bt1[(size_t)t*128 + b] = f2b(ldf(W1, (size_t)b*HC + t, bf));
  } else if (b < 384){
    int k = b - 128;
    Bt2[(size_t)t*256 + k] = f2b(ldf(W2, (size_t)k*HC + t, bf));
  } else {
    float p1 = ldf(We1, t, bf)*ldf(ae1, t, bf);
    float p2 = ldf(We2, t, bf)*ldf(ae2, t, bf);
    #pragma unroll
    for(int o=32;o>0;o>>=1){ p1+=__shfl_xor(p1,o); p2+=__shfl_xor(p2,o); }
    if((t&63)==0){ ce[t>>6]=p1; ce[4+(t>>6)]=p2; }
  }
}

// ---------------- 2-kernel scan (deg -> per-block exclusive rowptr + scanned bsums) ----------------
// consumers add bsums[i>>8]
__global__ void k_scan1(const int* __restrict__ in, int* __restrict__ out, int* __restrict__ bsums, int n){
  __shared__ int s[256];
  int t = threadIdx.x;
  int i = blockIdx.x*256 + t;
  int v = (i<n)? in[i] : 0;
  s[t]=v; __syncthreads();
  for(int off=1; off<256; off<<=1){
    int tv = (t>=off)? s[t-off] : 0;
    __syncthreads();
    s[t]+=tv; __syncthreads();
  }
  if (i<n) out[i] = s[t]-v;            // exclusive within block
  if (t==255) bsums[blockIdx.x] = s[255];
}

__global__ void k_scan2(int* __restrict__ bsums, int nb){
  __shared__ int s[256];
  int t=threadIdx.x;
  int v=(t<nb)? bsums[t]:0;
  s[t]=v; __syncthreads();
  for(int off=1; off<256; off<<=1){
    int tv=(t>=off)? s[t-off]:0;
    __syncthreads();
    s[t]+=tv; __syncthreads();
  }
  if (t<nb) bsums[t]=s[t]-v;
}

// ---------------- scatter: ATOMIC-FREE; one packed nontemporal 8B store per edge ----------------
// epk[p] = (ew_bits << 32) | src ; p = rowptr[d] + bsums[d>>8] + rank[e]
__global__ void k_scatter(const int* __restrict__ src, const int* __restrict__ dst,
                          const void* __restrict__ ew, int E, int N,
                          const int* __restrict__ rowptr, const int* __restrict__ bsums,
                          const int* __restrict__ rank, u64* __restrict__ epk,
                          const int* __restrict__ flagp){
  int e = blockIdx.x*256+threadIdx.x;
  if (e>=E) return;
  int bf = *flagp;
  int d = dst[e];
  if ((unsigned)d >= (unsigned)N) return;
  int p = rowptr[d] + bsums[d>>8] + rank[e];
  int s = src[e];
  if ((unsigned)s >= (unsigned)N) s = 0;
  u64 v = ((u64)__float_as_uint(ldf(ew, e, bf)) << 32) | (unsigned)s;
  __builtin_nontemporal_store(v, &epk[p]);
}

// ---------------- MFMA GEMM: C[m][0:256] = A[m][:]*B, tile 64x256, BK=32 ----------------
// B staged with global_load_lds (async DMA); A likewise when bf16 (internal always;
// external bf16 for full tiles). Also computes per-row attention dots in the epilogue.
__global__ __launch_bounds__(256) void k_gemm_mfma(
    const void* __restrict__ A, int a_ext, const u16* __restrict__ Bt,
    u16* __restrict__ C, const void* __restrict__ att_s, const void* __restrict__ att_d,
    float* __restrict__ a_s, float* __restrict__ a_d,
    int M, int K, const int* __restrict__ flagp)
{
  __shared__ u16 sh[64*264];           // 33 KB; K-loop: [As 2048][Bs 8192]; epilogue: 64x264 C tile
  __shared__ float att_sh[512];        // [0:256) att_s (f32), [256:512) att_d
  u16* As = sh;
  u16* Bs = sh + 2048;
  int bf = *flagp;
  int a_bf = a_ext ? bf : 1;
  int tid = threadIdx.x;
  int lane = tid & 63, w = tid >> 6;
  int quad = lane >> 4, ln = lane & 15;
  int m0 = blockIdx.x * 64;
  bool adma = (!a_ext) || (a_bf && (m0 + 64 <= M));   // DMA path valid (tail over-read safe only internal)

  att_sh[tid]       = ldf(att_s, tid, bf);
  att_sh[256 + tid] = ldf(att_d, tid, bf);

  f32x4v acc[4][4] = {};
  for (int k0 = 0; k0 < K; k0 += 32){
    // stage A tile 64x32
    if (adma){
      const u16* gA = (const u16*)A + (size_t)(m0 + (tid>>2))*K + k0 + (size_t)(tid&3)*8;
      glds16(gA, (char*)As + (size_t)w*1024);
    } else {
      int m = tid >> 2, g = tid & 3;
      int r = m0 + m;
      uint4 pack;
      if (r < M){
        size_t base = (size_t)r*K + k0 + g*8;
        if (a_bf){
          pack = *(const uint4*)((const u16*)A + base);
        } else {
          const float* Af = (const float*)A + base;
          float4 f0 = *(const float4*)Af;
          float4 f1 = *(const float4*)(Af+4);
          unsigned a0 = (unsigned)f2b(f0.x) | ((unsigned)f2b(f0.y)<<16);
          unsigned a1 = (unsigned)f2b(f0.z) | ((unsigned)f2b(f0.w)<<16);
          unsigned a2 = (unsigned)f2b(f1.x) | ((unsigned)f2b(f1.y)<<16);
          unsigned a3 = (unsigned)f2b(f1.z) | ((unsigned)f2b(f1.w)<<16);
          pack = make_uint4(a0,a1,a2,a3);
        }
      } else pack = make_uint4(0,0,0,0);
      ((uint4*)As)[tid] = pack;
    }
    // stage B tile 256x32 via async DMA ([n][k] bf16, always in-bounds)
    #pragma unroll
    for (int i=0;i<4;i++){
      const u16* gB = Bt + (size_t)(i*64 + (tid>>2))*K + k0 + (size_t)(tid&3)*8;
      glds16(gB, (char*)Bs + (size_t)i*4096 + (size_t)w*1024);
    }
    __syncthreads();
    bf16x8 af[4], bfr[4];
    #pragma unroll
    for (int mi=0;mi<4;mi++) af[mi] = *(const bf16x8*)&As[(mi*16+ln)*32 + quad*8];
    #pragma unroll
    for (int nj=0;nj<4;nj++) bfr[nj] = *(const bf16x8*)&Bs[((size_t)w*64+nj*16+ln)*32 + quad*8];
    #pragma unroll
    for (int mi=0;mi<4;mi++)
      #pragma unroll
      for (int nj=0;nj<4;nj++)
        acc[mi][nj] = __builtin_amdgcn_mfma_f32_16x16x32_bf16(af[mi], bfr[nj], acc[mi][nj], 0,0,0);
    __syncthreads();
  }
  // dump accumulators to LDS (C/D layout: row=quad*4+reg, col=lane&15), packed converts
  #pragma unroll
  for (int mi=0;mi<4;mi++)
    #pragma unroll
    for (int nj=0;nj<4;nj++){
      union { __hip_bfloat162 h2; u16 u[2]; } cv0, cv1;
      cv0.h2 = __float22bfloat162_rn(make_float2(acc[mi][nj][0], acc[mi][nj][1]));
      cv1.h2 = __float22bfloat162_rn(make_float2(acc[mi][nj][2], acc[mi][nj][3]));
      int col = w*64 + nj*16 + ln;
      int rbase = mi*16 + quad*4;
      sh[(rbase+0)*264 + col] = cv0.u[0];
      sh[(rbase+1)*264 + col] = cv0.u[1];
      sh[(rbase+2)*264 + col] = cv1.u[0];
      sh[(rbase+3)*264 + col] = cv1.u[1];
    }
  __syncthreads();
  // coalesced bulk store of the 64x256 bf16 tile
  #pragma unroll
  for (int j=0;j<8;j++){
    int idx = j*256 + tid;
    int r = idx >> 5, gq = idx & 31;
    if (m0 + r < M)
      *(uint4*)(C + (size_t)(m0+r)*HC + gq*8) = *(const uint4*)&sh[r*264 + gq*8];
  }
  // per-row attention dots, shuffle-free: lane l -> row w*16+(l&15), head l>>4.
  {
    int r  = w*16 + ln;
    int hh = quad;
    const u16* crow = &sh[r*264 + hh*64];
    const float* asv = &att_sh[hh*64];
    const float* adv = &att_sh[256 + hh*64];
    float ps = 0.f, pd = 0.f;
    #pragma unroll
    for (int cb=0; cb<64; cb+=8){
      ushort4 ua = *(const ushort4*)&crow[cb];
      ushort4 ub = *(const ushort4*)&crow[cb+4];
      float4 sa = *(const float4*)&asv[cb];
      float4 sb = *(const float4*)&asv[cb+4];
      float4 da = *(const float4*)&adv[cb];
      float4 db = *(const float4*)&adv[cb+4];
      float c0=b2f(ua.x), c1=b2f(ua.y), c2=b2f(ua.z), c3=b2f(ua.w);
      float c4=b2f(ub.x), c5=b2f(ub.y), c6=b2f(ub.z), c7=b2f(ub.w);
      ps += c0*sa.x + c1*sa.y + c2*sa.z + c3*sa.w + c4*sb.x + c5*sb.y + c6*sb.z + c7*sb.w;
      pd += c0*da.x + c1*da.y + c2*da.z + c3*da.w + c4*db.x + c5*db.y + c6*db.z + c7*db.w;
    }
    if (m0 + r < M){
      a_s[(size_t)(m0+r)*4 + hh] = ps;
      a_d[(size_t)(m0+r)*4 + hh] = pd;
    }
  }
}

// pair load: edges 2P,2P+1; lanes 0-31 carry edge 2P's row (16B each), lanes 32-63 edge 2P+1's.
#define PLOAD(P, DST) { \
  int sA_ = __builtin_amdgcn_readlane(s_reg, 2*(P)); \
  int sB_ = __builtin_amdgcn_readlane(s_reg, 2*(P)+1); \
  int ss_ = hf ? sB_ : sA_; \
  DST = *(const uint4*)&xs[(size_t)ss_*HC + (c32<<3)]; \
}
// apply: each lane fetches its own edge-weight (head c32>>3, edge 2P+hf) from TWJ, 8 features FMA
#define PAPPLY(P, XV, TWJ) { \
  float wk_ = wshf((TWJ), baseW4 + (((P)&7)<<3)); \
  v2f f_; \
  f_=(v2f){__uint_as_float((XV).x<<16),__uint_as_float((XV).x&0xFFFF0000u)}; av0+=f_*wk_; \
  f_=(v2f){__uint_as_float((XV).y<<16),__uint_as_float((XV).y&0xFFFF0000u)}; av1+=f_*wk_; \
  f_=(v2f){__uint_as_float((XV).z<<16),__uint_as_float((XV).z&0xFFFF0000u)}; av2+=f_*wk_; \
  f_=(v2f){__uint_as_float((XV).w<<16),__uint_as_float((XV).w&0xFFFF0000u)}; av3+=f_*wk_; \
}
#define PAIR2(P, TWJ) { uint4 xv_; PLOAD(P, xv_); PAPPLY(P, xv_, TWJ); }

// ---------------- fused segment softmax + aggregation + layer epilogue ----------------
// one wave per destination node, zero LDS, 2 waves/block. deg<=64: lane p owns edge p
// for softmax; aggregation processes edge PAIRS: one dwordx4 loads two edges' rows
// (half-wave each), one bpermute fetches each lane's edge-weight. Edges >= dg have
// exact weight 0 and s=0, so guards are chunk-level only. No max-subtract (logits |.|<~20).
__global__ __launch_bounds__(128) void k_soft_agg(
    const u16* __restrict__ xs, const int* __restrict__ rowptr, const int* __restrict__ bsums,
    const int* __restrict__ deg, const u64* __restrict__ epk,
    const float* __restrict__ a_s, const float* __restrict__ a_d, const float* __restrict__ ce4,
    const void* __restrict__ bias, void* __restrict__ outp, int N, int layer,
    const int* __restrict__ flagp){
  int bf = *flagp;
  int lane = threadIdx.x & 63;
  int w = threadIdx.x >> 6;
  int n = (blockIdx.x<<1) + w;
  if (n >= N) return;
  int c32 = lane & 31, hf = lane >> 5;
  int baseW4 = ((c32>>3)<<6) | (hf<<2);   // byte-lane addr of (head=c32>>3, edge-parity=hf)
  int row = rowptr[n] + bsums[n>>8];
  int dg = deg[n];
  float4 ad = *(const float4*)&a_d[(size_t)n*4];
  float4 ce = *(const float4*)ce4;
  int h = lane >> 4;
  // accumulators: features c32*8 + {0..7}; halves hold even/odd-edge partials
  v2f av0={0.f,0.f}, av1={0.f,0.f}, av2={0.f,0.f}, av3={0.f,0.f};
  if (dg > 0){
    if (dg <= 64){
      // --- edge record: lane p owns edge p; pad lanes get s=0, wv=0 ---
      u64 pk = 0;
      if (lane < dg) pk = epk[row + lane];
      int s = (int)(unsigned)(pk & 0xFFFFFFFFull);
      if ((unsigned)s >= (unsigned)N) s = 0;
      int s_reg = s;
      float wv = __uint_as_float((unsigned)(pk >> 32));
      // critical-path divergent gather (issue first)
      float4 as4 = *(const float4*)&a_s[(size_t)s*4];
      // prefetch first 4 pairs (edges 0..7); latency hides under softmax below
      uint4 xpf0, xpf1, xpf2, xpf3;
      PLOAD(0, xpf0); PLOAD(1, xpf1); PLOAD(2, xpf2); PLOAD(3, xpf3);
      // --- logits -> exp (no max-subtract; pads forced to 0) ---
      bool vlane = lane < dg;
      float4 ex;
      ex.x = vlane ? __expf(lrelu(as4.x+ad.x+wv*ce.x)) : 0.f;
      ex.y = vlane ? __expf(lrelu(as4.y+ad.y+wv*ce.y)) : 0.f;
      ex.z = vlane ? __expf(lrelu(as4.z+ad.z+wv*ce.z)) : 0.f;
      ex.w = vlane ? __expf(lrelu(as4.w+ad.w+wv*ce.w)) : 0.f;
      // --- deg-adaptive sum butterfly ---
      float4 ss = ex;
      if (dg > 32){
        ss.x+=__shfl_xor(ss.x,32); ss.y+=__shfl_xor(ss.y,32);
        ss.z+=__shfl_xor(ss.z,32); ss.w+=__shfl_xor(ss.w,32);
      }
      if (dg > 16){
        ss.x+=__shfl_xor(ss.x,16); ss.y+=__shfl_xor(ss.y,16);
        ss.z+=__shfl_xor(ss.z,16); ss.w+=__shfl_xor(ss.w,16);
      }
      #pragma unroll
      for(int o=8;o>0;o>>=1){
        ss.x+=__shfl_xor(ss.x,o); ss.y+=__shfl_xor(ss.y,o);
        ss.z+=__shfl_xor(ss.z,o); ss.w+=__shfl_xor(ss.w,o);
      }
      float4 wgt;
      wgt.x = ex.x/(ss.x+1e-16f); wgt.y = ex.y/(ss.y+1e-16f);
      wgt.z = ex.z/(ss.z+1e-16f); wgt.w = ex.w/(ss.w+1e-16f);
      // --- transpose: twJ lane l = head-(l>>4) weight of edge J*16+(l&15) ---
      float tw0, tw1, tw2, tw3;
      {
        int srcl = lane & 15;
        float c0=__shfl(wgt.x,srcl), c1=__shfl(wgt.y,srcl);
        float c2=__shfl(wgt.z,srcl), c3=__shfl(wgt.w,srcl);
        tw0 = (h==0)?c0:((h==1)?c1:((h==2)?c2:c3));
      }
      if (dg > 16){
        int srcl = 16 + (lane & 15);
        float c0=__shfl(wgt.x,srcl), c1=__shfl(wgt.y,srcl);
        float c2=__shfl(wgt.z,srcl), c3=__shfl(wgt.w,srcl);
        tw1 = (h==0)?c0:((h==1)?c1:((h==2)?c2:c3));
      } else tw1 = 0.f;
      if (dg > 32){
        int srcl = 32 + (lane & 15);
        float c0=__shfl(wgt.x,srcl), c1=__shfl(wgt.y,srcl);
        float c2=__shfl(wgt.z,srcl), c3=__shfl(wgt.w,srcl);
        tw2 = (h==0)?c0:((h==1)?c1:((h==2)?c2:c3));
      } else tw2 = 0.f;
      if (dg > 48){
        int srcl = 48 + (lane & 15);
        float c0=__shfl(wgt.x,srcl), c1=__shfl(wgt.y,srcl);
        float c2=__shfl(wgt.z,srcl), c3=__shfl(wgt.w,srcl);
        tw3 = (h==0)?c0:((h==1)?c1:((h==2)?c2:c3));
      } else tw3 = 0.f;
      // --- aggregation: prefetched pairs first, then chunked guarded pairs ---
      PAPPLY(0, xpf0, tw0); PAPPLY(1, xpf1, tw0);
      PAPPLY(2, xpf2, tw0); PAPPLY(3, xpf3, tw0);
      if (dg >  8){ PAIR2(4, tw0); PAIR2(5, tw0); }
      if (dg > 12){ PAIR2(6, tw0); PAIR2(7, tw0); }
      if (dg > 16){ PAIR2(8, tw1); PAIR2(9, tw1);
        if (dg > 20){ PAIR2(10, tw1); PAIR2(11, tw1); }
        if (dg > 24){ PAIR2(12, tw1); PAIR2(13, tw1); }
        if (dg > 28){ PAIR2(14, tw1); PAIR2(15, tw1); }
        if (dg > 32){ PAIR2(16, tw2); PAIR2(17, tw2);
          if (dg > 36){ PAIR2(18, tw2); PAIR2(19, tw2); }
          if (dg > 40){ PAIR2(20, tw2); PAIR2(21, tw2); }
          if (dg > 44){ PAIR2(22, tw2); PAIR2(23, tw2); }
          if (dg > 48){ PAIR2(24, tw3); PAIR2(25, tw3);
            if (dg > 52){ PAIR2(26, tw3); PAIR2(27, tw3); }
            if (dg > 56){ PAIR2(28, tw3); PAIR2(29, tw3); }
            if (dg > 60){ PAIR2(30, tw3); PAIR2(31, tw3); }
          }
        }
      }
    } else {
      // fallback: recompute; halves split edges by parity so cross-half add stays correct
      float4 m = make_float4(-1e30f,-1e30f,-1e30f,-1e30f);
      for (int p=lane;p<dg;p+=64){
        u64 pk = epk[row+p];
        int s = (int)(unsigned)(pk & 0xFFFFFFFFull);
        if ((unsigned)s >= (unsigned)N) s = 0;
        float wv = __uint_as_float((unsigned)(pk >> 32));
        float4 as = *(const float4*)&a_s[(size_t)s*4];
        m.x=fmaxf(m.x, lrelu(as.x+ad.x+wv*ce.x));
        m.y=fmaxf(m.y, lrelu(as.y+ad.y+wv*ce.y));
        m.z=fmaxf(m.z, lrelu(as.z+ad.z+wv*ce.z));
        m.w=fmaxf(m.w, lrelu(as.w+ad.w+wv*ce.w));
      }
      m = wave_max4(m);
      float4 sv = make_float4(0.f,0.f,0.f,0.f);
      for (int p=lane;p<dg;p+=64){
        u64 pk = epk[row+p];
        int s = (int)(unsigned)(pk & 0xFFFFFFFFull);
        if ((unsigned)s >= (unsigned)N) s = 0;
        float wv = __uint_as_float((unsigned)(pk >> 32));
        float4 as = *(const float4*)&a_s[(size_t)s*4];
        sv.x+=__expf(lrelu(as.x+ad.x+wv*ce.x)-m.x);
        sv.y+=__expf(lrelu(as.y+ad.y+wv*ce.y)-m.y);
        sv.z+=__expf(lrelu(as.z+ad.z+wv*ce.z)-m.z);
        sv.w+=__expf(lrelu(as.w+ad.w+wv*ce.w)-m.w);
      }
      sv = wave_sum4(sv);
      int hq = c32 >> 3;
      float rsel=1.f/(sel4(sv,hq)+1e-16f), mh=sel4(m,hq), adh=sel4(ad,hq), ceh=sel4(ce,hq);
      for (int e=hf;e<dg;e+=2){
        u64 pk = epk[row+e];
        int s = (int)(unsigned)(pk & 0xFFFFFFFFull);
        if ((unsigned)s >= (unsigned)N) s = 0;
        float wv = __uint_as_float((unsigned)(pk >> 32));
        float arv = lrelu(a_s[(size_t)s*4+hq]+adh+wv*ceh);
        float wk = __expf(arv-mh)*rsel;
        uint4 xv = *(const uint4*)&xs[(size_t)s*HC + (c32<<3)];
        v2f f;
        f=(v2f){__uint_as_float(xv.x<<16),__uint_as_float(xv.x&0xFFFF0000u)}; av0+=f*wk;
        f=(v2f){__uint_as_float(xv.y<<16),__uint_as_float(xv.y&0xFFFF0000u)}; av1+=f*wk;
        f=(v2f){__uint_as_float(xv.z<<16),__uint_as_float(xv.z&0xFFFF0000u)}; av2+=f*wk;
        f=(v2f){__uint_as_float(xv.w<<16),__uint_as_float(xv.w&0xFFFF0000u)}; av3+=f*wk;
      }
    }
  }
  // --- cross-half combine: av now = full edge sum, features c32*8+{0..7} ---
  float vb0=av0.x, vb1=av0.y, vb2=av1.x, vb3=av1.y, vb4=av2.x, vb5=av2.y, vb6=av3.x, vb7=av3.y;
  vb0+=__shfl_xor(vb0,32); vb1+=__shfl_xor(vb1,32); vb2+=__shfl_xor(vb2,32); vb3+=__shfl_xor(vb3,32);
  vb4+=__shfl_xor(vb4,32); vb5+=__shfl_xor(vb5,32); vb6+=__shfl_xor(vb6,32); vb7+=__shfl_xor(vb7,32);
  if (layer==1){
    // h = relu(l2norm(acc + b1)) -> bf16
    int fb = c32 << 3;
    vb0 += ldf(bias, fb+0, bf); vb1 += ldf(bias, fb+1, bf);
    vb2 += ldf(bias, fb+2, bf); vb3 += ldf(bias, fb+3, bf);
    vb4 += ldf(bias, fb+4, bf); vb5 += ldf(bias, fb+5, bf);
    vb6 += ldf(bias, fb+6, bf); vb7 += ldf(bias, fb+7, bf);
    float ss = vb0*vb0+vb1*vb1+vb2*vb2+vb3*vb3+vb4*vb4+vb5*vb5+vb6*vb6+vb7*vb7;
    #pragma unroll
    for(int o=16;o>0;o>>=1) ss += __shfl_xor(ss,o);
    float inv = 1.f/fmaxf(sqrtf(ss), 1e-12f);
    if (hf==0){
      union { u16 u[8]; uint4 v; } pk8;
      pk8.u[0]=f2b(fmaxf(vb0*inv,0.f)); pk8.u[1]=f2b(fmaxf(vb1*inv,0.f));
      pk8.u[2]=f2b(fmaxf(vb2*inv,0.f)); pk8.u[3]=f2b(fmaxf(vb3*inv,0.f));
      pk8.u[4]=f2b(fmaxf(vb4*inv,0.f)); pk8.u[5]=f2b(fmaxf(vb5*inv,0.f));
      pk8.u[6]=f2b(fmaxf(vb6*inv,0.f)); pk8.u[7]=f2b(fmaxf(vb7*inv,0.f));
      *(uint4*)((u16*)outp + (size_t)n*HC + fb) = pk8.v;
    }
  } else {
    // mean over heads + b2 -> final output; head bits of c32 are bits 3,4
    vb0+=__shfl_xor(vb0,8);  vb1+=__shfl_xor(vb1,8);  vb2+=__shfl_xor(vb2,8);  vb3+=__shfl_xor(vb3,8);
    vb4+=__shfl_xor(vb4,8);  vb5+=__shfl_xor(vb5,8);  vb6+=__shfl_xor(vb6,8);  vb7+=__shfl_xor(vb7,8);
    vb0+=__shfl_xor(vb0,16); vb1+=__shfl_xor(vb1,16); vb2+=__shfl_xor(vb2,16); vb3+=__shfl_xor(vb3,16);
    vb4+=__shfl_xor(vb4,16); vb5+=__shfl_xor(vb5,16); vb6+=__shfl_xor(vb6,16); vb7+=__shfl_xor(vb7,16);
    if (hf==0 && c32 < 8){
      int cb = c32 << 3;
      float o0 = 0.25f*vb0 + ldf(bias, cb+0, bf);
      float o1 = 0.25f*vb1 + ldf(bias, cb+1, bf);
      float o2 = 0.25f*vb2 + ldf(bias, cb+2, bf);
      float o3 = 0.25f*vb3 + ldf(bias, cb+3, bf);
      float o4 = 0.25f*vb4 + ldf(bias, cb+4, bf);
      float o5 = 0.25f*vb5 + ldf(bias, cb+5, bf);
      float o6 = 0.25f*vb6 + ldf(bias, cb+6, bf);
      float o7 = 0.25f*vb7 + ldf(bias, cb+7, bf);
      if (bf){
        union { u16 u[8]; uint4 v; } pk8;
        pk8.u[0]=f2b(o0); pk8.u[1]=f2b(o1); pk8.u[2]=f2b(o2); pk8.u[3]=f2b(o3);
        pk8.u[4]=f2b(o4); pk8.u[5]=f2b(o5); pk8.u[6]=f2b(o6); pk8.u[7]=f2b(o7);
        *(uint4*)((u16*)outp + (size_t)n*CDIM + cb) = pk8.v;
      } else {
        float* of = (float*)outp + (size_t)n*CDIM + cb;
        *(float4*)of     = make_float4(o0,o1,o2,o3);
        *(float4*)(of+4) = make_float4(o4,o5,o6,o7);
      }
    }
  }
}

extern "C" void kernel_launch(void* const* d_in, const int* in_sizes, int n_in,
                              void* d_out, int out_size, void* d_ws, size_t ws_size,
                              hipStream_t stream){
  const void* x_in = d_in[0];
  const int* eidx  = (const int*)d_in[1];
  const void* ew   = d_in[2];
  const void* W1   = d_in[3];
  const void* as1  = d_in[4];
  const void* ad1  = d_in[5];
  const void* We1  = d_in[6];
  const void* ae1  = d_in[7];
  const void* b1   = d_in[8];
  const void* W2   = d_in[9];
  const void* as2  = d_in[10];
  const void* ad2  = d_in[11];
  const void* We2  = d_in[12];
  const void* ae2  = d_in[13];
  const void* b2   = d_in[14];

  int N = in_sizes[0]/128;
  int E = in_sizes[2];
  const int* src = eidx;
  const int* dst = eidx + E;

  char* w = (char*)d_ws;
  auto alloc = [&](size_t bytes)->char*{ char* p=w; w += (bytes+255)/256*256; return p; };
  int*   flag  = (int*)alloc(256);
  u16*   xs    = (u16*)alloc((size_t)N*HC*2);   // bf16 feature buffer A
  u16*   agg   = (u16*)alloc((size_t)N*HC*2);   // bf16 feature buffer B (h); GEMM2 tail over-reads into a_s (safe)
  float* a_s   = (float*)alloc((size_t)N*4*4);
  float* a_d   = (float*)alloc((size_t)N*4*4);
  int*   deg   = (int*)alloc((size_t)N*4);
  int*   rowptr= (int*)alloc((size_t)N*4);
  int*   bsums = (int*)alloc(256*4);
  int*   rank  = (int*)alloc((size_t)E*4);      // per-edge rank within dst bucket
  u64*   epk   = (u64*)alloc((size_t)E*8);      // packed (ew<<32 | src) per edge
  float* ce    = (float*)alloc(256);            // [0:4)=layer1, [4:8)=layer2
  u16*   Bt1   = (u16*)alloc((size_t)HC*128*2); // W1^T bf16 [256][128]
  u16*   Bt2   = (u16*)alloc((size_t)HC*HC*2);  // W2^T bf16 [256][256]

  (void)hipMemsetAsync(deg, 0, (size_t)N*4, stream);

  int eb = (E+255)/256;
  int nb = (N+255)/256;
  k_hist_prep<<<eb+385,256,0,stream>>>(dst, E, N, deg, rank, (const u16*)x_in, in_sizes[0], flag,
                                       W1, W2, We1, ae1, We2, ae2, Bt1, Bt2, ce);
  k_scan1<<<nb,256,0,stream>>>(deg, rowptr, bsums, N);
  k_scan2<<<1,256,0,stream>>>(bsums, nb);
  k_scatter<<<eb,256,0,stream>>>(src, dst, ew, E, N, rowptr, bsums, rank, epk, flag);

  int gemmBlocks = (N+63)/64;
  int nwb = (N+1)/2;   // 2 node-waves per block

  // ---- layer 1 ----
  k_gemm_mfma<<<gemmBlocks,256,0,stream>>>(x_in, 1, Bt1, xs, as1, ad1, a_s, a_d, N, 128, flag);
  k_soft_agg<<<nwb,128,0,stream>>>(xs, rowptr, bsums, deg, epk, a_s, a_d, ce, b1, agg, N, 1, flag);

  // ---- layer 2 ----
  k_gemm_mfma<<<gemmBlocks,256,0,stream>>>(agg, 0, Bt2, xs, as2, ad2, a_s, a_d, N, 256, flag);
  k_soft_agg<<<nwb,128,0,stream>>>(xs, rowptr, bsums, deg, epk, a_s, a_d, ce+4, b2, d_out, N, 2, flag);
}